// Round 16
// baseline (682.865 us; speedup 1.0000x reference)
//
#include <hip/hip_runtime.h>
#include <cstdint>

#define N_NODESC 50000
#define N_EDGESC 500000
#define E_TOT    550000
#define DIM      144
#define NGRAPH   64
#define EPSV     1e-5f
#define SCAN_NB  ((N_NODESC + 511)/512)

typedef __attribute__((ext_vector_type(8))) short bf16x8;
typedef __attribute__((ext_vector_type(4))) float f32x4;

__device__ __forceinline__ float lrelu(float x){ return x > 0.f ? x : 0.2f*x; }

__device__ __forceinline__ unsigned short f2bf(float f){
  unsigned u = __float_as_uint(f);
  u += 0x7FFF + ((u >> 16) & 1);
  return (unsigned short)(u >> 16);
}
__device__ __forceinline__ float bf2f(unsigned short b){
  return __uint_as_float(((unsigned)b) << 16);
}

// ---------------- CSR build (by dst, self-loops appended) ----------------
__global__ void k_count(const int* __restrict__ ei, int* __restrict__ deg){
  int e = blockIdx.x*blockDim.x + threadIdx.x;
  if (e >= E_TOT) return;
  int d = (e < N_EDGESC) ? ei[N_EDGESC + e] : (e - N_EDGESC);
  atomicAdd(&deg[d], 1);
}

__global__ __launch_bounds__(256) void k_scan1(const int* __restrict__ deg,
    int* __restrict__ scanned, int* __restrict__ bsum){
  __shared__ int ls[256];
  int b = blockIdx.x, t = threadIdx.x;
  int i0 = b*512 + 2*t;
  int e0 = (i0   < N_NODESC) ? deg[i0]   : 0;
  int e1 = (i0+1 < N_NODESC) ? deg[i0+1] : 0;
  int s = e0 + e1;
  ls[t] = s;
  __syncthreads();
  #pragma unroll
  for (int ofs=1; ofs<256; ofs<<=1){
    int v = (t >= ofs) ? ls[t-ofs] : 0;
    __syncthreads();
    ls[t] += v;
    __syncthreads();
  }
  int excl = ls[t] - s;
  if (i0   < N_NODESC) scanned[i0]   = excl;
  if (i0+1 < N_NODESC) scanned[i0+1] = excl + e0;
  if (t == 255) bsum[b] = ls[255];
}

__global__ void k_scan2(int* __restrict__ bsum){
  __shared__ int ls[128];
  int t = threadIdx.x;
  int v = (t < SCAN_NB) ? bsum[t] : 0;
  ls[t] = v;
  __syncthreads();
  #pragma unroll
  for (int ofs=1; ofs<128; ofs<<=1){
    int u = (t >= ofs) ? ls[t-ofs] : 0;
    __syncthreads();
    ls[t] += u;
    __syncthreads();
  }
  if (t < SCAN_NB) bsum[t] = ls[t] - v;
}

__global__ __launch_bounds__(256) void k_scan3(const int* __restrict__ scanned,
    const int* __restrict__ bsum, int* __restrict__ row_ptr, int* __restrict__ cursor){
  int i = blockIdx.x*blockDim.x + threadIdx.x;
  if (i < N_NODESC){
    int v = scanned[i] + bsum[i >> 9];
    row_ptr[i] = v; cursor[i] = v;
  }
  if (i == 0) row_ptr[N_NODESC] = E_TOT;
}

__global__ void k_scatter(const int* __restrict__ ei, int* __restrict__ cursor,
                          int* __restrict__ col){
  int e = blockIdx.x*blockDim.x + threadIdx.x;
  if (e >= E_TOT) return;
  int s, d;
  if (e < N_EDGESC){ s = ei[e]; d = ei[N_EDGESC + e]; } else { s = e - N_EDGESC; d = s; }
  int pos = atomicAdd(&cursor[d], 1);
  col[pos] = s;
}

// ---------------- weight prep: W'' = diag(sc)*W (+attn-logit cols), bf16, transposed ----------------
__global__ __launch_bounds__(192) void k_prep_w(
    const float* __restrict__ W, const float* __restrict__ bias_in,
    const float* __restrict__ a_s, const float* __restrict__ a_d,
    const float* __restrict__ bnsum, const float* __restrict__ bngam,
    const float* __restrict__ bnbet,
    unsigned short* __restrict__ Wt, float* __restrict__ bias2,
    int K, int SK, int H){
  __shared__ float red[256];
  int np = blockIdx.x, k = threadIdx.x;
  float sc = 1.f, sh = 0.f;
  if (k < K && bnsum){
    float mu  = bnsum[k] * (1.f/N_NODESC);
    float var = bnsum[K+k] * (1.f/N_NODESC) - mu*mu;
    float inv = rsqrtf(var + EPSV);
    sc = inv * bngam[k];
    sh = bnbet[k] - mu*sc;
  }
  float wcomb = 0.f;
  if (k < K){
    if (np < 144) wcomb = W[(size_t)k*144 + np];
    else if (H > 0){
      int c = np - 144;
      bool iss = c < 8;
      int h = iss ? c : c - 8;
      if (h < H){
        const float* av = iss ? a_s : a_d;
        int C = 144 / H;
        for (int j=0;j<C;++j) wcomb += W[(size_t)k*144 + h*C + j] * av[h*C + j];
      }
    }
  }
  if (k < SK) Wt[(size_t)np*SK + k] = f2bf(wcomb*sc);
  red[k] = (k < K) ? sh*wcomb : 0.f;
  if (k < 64) red[k+192] = 0.f;
  __syncthreads();
  #pragma unroll
  for (int s=128; s>0; s>>=1){
    if (k < s) red[k] += red[k+s];
    __syncthreads();
  }
  if (k == 0){
    float b = red[0];
    if (np < 144 && bias_in) b += bias_in[np];
    bias2[np] = b;
  }
}

// ---------------- MFMA GEMM with LDS-staged Wt; optional f32 A (fused cast) ----------------
template<int NT, int KS, int SK, int NROW, int AF32>
__global__ __launch_bounds__(256) void k_mfma_gemm(
    const void* __restrict__ Av,
    const unsigned short* __restrict__ Wt,
    const float* __restrict__ bias2,
    unsigned short* __restrict__ hp,
    float* __restrict__ al_s, float* __restrict__ al_d,
    int KA, int H){
  __shared__ unsigned short sW[NROW*SK];
  int t = threadIdx.x;
  for (int i = t; i < NROW*SK/8; i += 256)
    ((uint4*)sW)[i] = ((const uint4*)Wt)[i];
  __syncthreads();

  int wave = t >> 6, lane = t & 63;
  int c = lane & 15, quad = lane >> 4;
  int m_base = blockIdx.x*64 + wave*16;
  int mA = m_base + c; if (mA > N_NODESC-1) mA = N_NODESC-1;
  f32x4 acc[NT];
  #pragma unroll
  for (int i=0;i<NT;++i) acc[i] = (f32x4){0.f,0.f,0.f,0.f};
  #pragma unroll
  for (int ks=0; ks<KS; ++ks){
    bf16x8 af;
    if (AF32){
      const float* Arow = (const float*)Av + (size_t)mA*KA + quad*8;
      float4 f0 = *(const float4*)(Arow + ks*32);
      float4 f1 = *(const float4*)(Arow + ks*32 + 4);
      unsigned short tmp[8] = { f2bf(f0.x),f2bf(f0.y),f2bf(f0.z),f2bf(f0.w),
                                f2bf(f1.x),f2bf(f1.y),f2bf(f1.z),f2bf(f1.w) };
      af = *(const bf16x8*)tmp;
    } else {
      const unsigned short* Arow = (const unsigned short*)Av + (size_t)mA*KA + quad*8;
      af = *(const bf16x8*)(Arow + ks*32);
    }
    #pragma unroll
    for (int tt=0; tt<NT; ++tt){
      bf16x8 bfr = *(const bf16x8*)(sW + (tt*16 + c)*SK + ks*32 + quad*8);
      acc[tt] = __builtin_amdgcn_mfma_f32_16x16x32_bf16(af, bfr, acc[tt], 0, 0, 0);
    }
  }
  #pragma unroll
  for (int tt=0; tt<NT; ++tt){
    int n = tt*16 + c;
    float b = bias2[n];
    #pragma unroll
    for (int r=0;r<4;++r){
      int m = m_base + quad*4 + r;
      if (m < N_NODESC){
        float v = acc[tt][r] + b;
        if (n < 144){
          hp[(size_t)m*144 + n] = f2bf(v);
        } else {
          int cc = n - 144;
          if (cc < 8){ if (cc < H) al_s[m*H + cc] = v; }
          else { int h = cc - 8; if (h < H) al_d[m*H + h] = v; }
        }
      }
    }
  }
}

// ---------------- segment softmax: online pass -> normalized bf16 weights ----------------
// Pass: gather scores -> esc raw (f32 scratch), online max+den. Final loop:
// wN = bf16(exp(sc - m)/den)  — fully normalized; aggregate needs no den.
#define EB 8
__global__ __launch_bounds__(256) void k_edge_softmax(
    const float* __restrict__ al_s, const float* __restrict__ al_d,
    const int* __restrict__ row_ptr, const int* __restrict__ col,
    float* __restrict__ esc, unsigned short* __restrict__ wN, int H){
  int idx = blockIdx.x*blockDim.x + threadIdx.x;
  if (idx >= N_NODESC*H) return;
  int n = idx / H, h = idx - n*H;
  int p0 = row_ptr[n], p1 = row_ptr[n+1];
  float ald = al_d[idx];
  float m = -3.4e38f, d = 0.f;
  for (int base = p0; base < p1; base += EB){
    int cnt = min(EB, p1 - base);
    int ss[EB];
    #pragma unroll
    for (int i=0;i<EB;++i) if (i<cnt) ss[i] = col[base+i];
    float sc[EB];
    #pragma unroll
    for (int i=0;i<EB;++i) if (i<cnt) sc[i] = lrelu(al_s[ss[i]*H + h] + ald);
    float bm = -3.4e38f;
    #pragma unroll
    for (int i=0;i<EB;++i) if (i<cnt){
      esc[(size_t)(base+i)*H + h] = sc[i];
      bm = fmaxf(bm, sc[i]);
    }
    if (bm > m){ d *= __expf(m - bm); m = bm; }
    #pragma unroll
    for (int i=0;i<EB;++i) if (i<cnt) d += __expf(sc[i] - m);
  }
  float inv = 1.f/(d + 1e-16f);
  for (int e = p0; e < p1; ++e)
    wN[(size_t)e*H + h] = f2bf(__expf(esc[(size_t)e*H + h] - m) * inv);
}

// ---------------- weighted gather: 36 threads/node, uint2 (4-channel) loads ----------------
// Normalized bf16 weights; channel pairs never span heads (C even), but a
// uint2 (2 pairs) can -> load two weights per edge.
__global__ __launch_bounds__(256) void k_aggregate2(
    const uint2* __restrict__ hp4, const unsigned short* __restrict__ wN,
    const int* __restrict__ row_ptr, const int* __restrict__ col,
    const float* __restrict__ bias, uint2* __restrict__ out,
    int H, int C2){            // C2 = channel-pairs per head (9 or 72)
  int idx = blockIdx.x*blockDim.x + threadIdx.x;
  if (idx >= N_NODESC*36) return;
  int n = idx / 36, cp2 = idx - n*36;
  int h0 = (2*cp2) / C2, h1 = (2*cp2 + 1) / C2;
  int p0 = row_ptr[n], p1 = row_ptr[n+1];
  float a0=0.f, a1=0.f, a2=0.f, a3=0.f;
  for (int base = p0; base < p1; base += EB){
    int cnt = min(EB, p1 - base);
    int ss[EB]; float w0[EB], w1[EB];
    #pragma unroll
    for (int i=0;i<EB;++i) if (i<cnt){
      ss[i] = col[base+i];
      w0[i] = bf2f(wN[(size_t)(base+i)*H + h0]);
      w1[i] = bf2f(wN[(size_t)(base+i)*H + h1]);
    }
    uint2 vv[EB];
    #pragma unroll
    for (int i=0;i<EB;++i) if (i<cnt) vv[i] = hp4[(size_t)ss[i]*36 + cp2];
    #pragma unroll
    for (int i=0;i<EB;++i) if (i<cnt){
      a0 = fmaf(w0[i], __uint_as_float(vv[i].x << 16), a0);
      a1 = fmaf(w0[i], __uint_as_float(vv[i].x & 0xFFFF0000u), a1);
      a2 = fmaf(w1[i], __uint_as_float(vv[i].y << 16), a2);
      a3 = fmaf(w1[i], __uint_as_float(vv[i].y & 0xFFFF0000u), a3);
    }
  }
  int c0 = 4*cp2;
  float r0 = fmaxf(a0 + bias[c0],   0.f);
  float r1 = fmaxf(a1 + bias[c0+1], 0.f);
  float r2 = fmaxf(a2 + bias[c0+2], 0.f);
  float r3 = fmaxf(a3 + bias[c0+3], 0.f);
  uint2 o;
  o.x = (unsigned)f2bf(r0) | ((unsigned)f2bf(r1) << 16);
  o.y = (unsigned)f2bf(r2) | ((unsigned)f2bf(r3) << 16);
  out[(size_t)n*36 + cp2] = o;
}

// ---------------- batchnorm stats: two-stage, atomic-free ----------------
#define BNS_GRID 512
__global__ __launch_bounds__(256) void k_bnstats1(const uint2* __restrict__ h4,
                                                  float* __restrict__ partials){
  __shared__ float red[252*8];
  int t = threadIdx.x;
  int r = t / 36, c = t - r*36;
  bool active = (t < 252);
  int rows = (N_NODESC + BNS_GRID - 1)/BNS_GRID;
  int n0 = blockIdx.x*rows, n1 = min(N_NODESC, n0+rows);
  float s[4] = {0,0,0,0}, q[4] = {0,0,0,0};
  if (active){
    for (int n = n0 + r; n < n1; n += 7){
      uint2 v = h4[(size_t)n*36 + c];
      float f0 = __uint_as_float(v.x << 16);
      float f1 = __uint_as_float(v.x & 0xFFFF0000u);
      float f2 = __uint_as_float(v.y << 16);
      float f3 = __uint_as_float(v.y & 0xFFFF0000u);
      s[0]+=f0; q[0]+=f0*f0; s[1]+=f1; q[1]+=f1*f1;
      s[2]+=f2; q[2]+=f2*f2; s[3]+=f3; q[3]+=f3*f3;
    }
    #pragma unroll
    for (int j=0;j<4;++j){
      red[(c*7+r)*8 + j]     = s[j];
      red[(c*7+r)*8 + 4 + j] = q[j];
    }
  }
  __syncthreads();
  if (t < 36){
    float ss[4]={0,0,0,0}, qq[4]={0,0,0,0};
    for (int rr=0; rr<7; ++rr){
      #pragma unroll
      for (int j=0;j<4;++j){
        ss[j] += red[(t*7+rr)*8 + j];
        qq[j] += red[(t*7+rr)*8 + 4 + j];
      }
    }
    float* p = partials + (size_t)blockIdx.x*288;
    #pragma unroll
    for (int j=0;j<4;++j){
      p[4*t+j]       = ss[j];
      p[144+4*t+j]   = qq[j];
    }
  }
}

__global__ __launch_bounds__(64) void k_bnstats2(const float* __restrict__ partials,
                                                 float* __restrict__ sums){
  int i = blockIdx.x, t = threadIdx.x;
  float s = 0.f;
  for (int b = t; b < BNS_GRID; b += 64) s += partials[(size_t)b*288 + i];
  #pragma unroll
  for (int o=32; o>0; o>>=1) s += __shfl_xor(s, o, 64);
  if (t == 0) sums[i] = s;
}

// ---------------- per-graph mean pool over bf16 hA (32 parts/graph) ----------------
__device__ int lbound(const int* a, int n, int v){
  int lo = 0, hi = n;
  while (lo < hi){ int m = (lo+hi) >> 1; if (a[m] < v) lo = m+1; else hi = m; }
  return lo;
}

__global__ __launch_bounds__(128) void k_pool(const unsigned* __restrict__ h2,
    const int* __restrict__ batch, float* __restrict__ sums, int* __restrict__ cnts){
  int g = blockIdx.x & 63, part = blockIdx.x >> 6;
  __shared__ int sb[2];
  if (threadIdx.x == 0){ sb[0] = lbound(batch, N_NODESC, g); sb[1] = lbound(batch, N_NODESC, g+1); }
  __syncthreads();
  int lo = sb[0], hi = sb[1];
  int t = threadIdx.x;
  if (t < 72){
    float a0 = 0.f, a1 = 0.f;
    for (int n = lo + part; n < hi; n += 32){
      unsigned v = h2[(size_t)n*72 + t];
      a0 += __uint_as_float(v << 16);
      a1 += __uint_as_float(v & 0xFFFF0000u);
    }
    atomicAdd(&sums[g*DIM + 2*t],   a0);
    atomicAdd(&sums[g*DIM + 2*t+1], a1);
  }
  if (t == 0 && part == 0) cnts[g] = hi - lo;
}

// ---------------- MLP head: column-parallel, BN via wave reduction ----------------
__global__ __launch_bounds__(64) void k_mlp1(const float* __restrict__ psum,
    const int* __restrict__ cnts,
    const float* __restrict__ bn3, const float* __restrict__ gam3,
    const float* __restrict__ bet3,
    const float* __restrict__ M1, const float* __restrict__ bm1,
    const float* __restrict__ gm1, const float* __restrict__ bb1,
    float* __restrict__ h1){
  __shared__ float sSc[144], sSh[144];
  int t = threadIdx.x, c = blockIdx.x;
  for (int i=t; i<144; i+=64){
    float mu  = bn3[i] * (1.f/N_NODESC);
    float var = bn3[144+i] * (1.f/N_NODESC) - mu*mu;
    float sc  = rsqrtf(var + EPSV) * gam3[i];
    sSc[i] = sc; sSh[i] = bet3[i] - mu*sc;
  }
  __syncthreads();
  float invc = 1.f / (float)max(cnts[t], 1);
  float acc = bm1[c];
  const float* pr = psum + t*144;
  for (int k=0; k<144; ++k){
    float g = fmaf(pr[k]*invc, sSc[k], sSh[k]);
    acc = fmaf(g, M1[k*72 + c], acc);
  }
  float s = acc, q = acc*acc;
  #pragma unroll
  for (int o=32; o>0; o>>=1){ s += __shfl_xor(s, o, 64); q += __shfl_xor(q, o, 64); }
  float mu = s*(1.f/64.f), var = q*(1.f/64.f) - mu*mu;
  float v = (acc - mu)*rsqrtf(var + EPSV)*gm1[c] + bb1[c];
  h1[t*72 + c] = fmaxf(v, 0.f);
}

__global__ __launch_bounds__(64) void k_mlp2(const float* __restrict__ h1,
    const float* __restrict__ M2, const float* __restrict__ bm2,
    const float* __restrict__ gm2, const float* __restrict__ bb2,
    float* __restrict__ h2){
  int t = threadIdx.x, c = blockIdx.x;
  float acc = bm2[c];
  const float* pr = h1 + t*72;
  for (int k=0; k<72; ++k) acc = fmaf(pr[k], M2[k*36 + c], acc);
  float s = acc, q = acc*acc;
  #pragma unroll
  for (int o=32; o>0; o>>=1){ s += __shfl_xor(s, o, 64); q += __shfl_xor(q, o, 64); }
  float mu = s*(1.f/64.f), var = q*(1.f/64.f) - mu*mu;
  float v = (acc - mu)*rsqrtf(var + EPSV)*gm2[c] + bb2[c];
  h2[t*36 + c] = fmaxf(v, 0.f);
}

__global__ __launch_bounds__(64) void k_mlp3(const float* __restrict__ h2,
    const float* __restrict__ M3, const float* __restrict__ bm3,
    float* __restrict__ out){
  int t = threadIdx.x, c = blockIdx.x;
  float acc = bm3[c];
  const float* pr = h2 + t*36;
  for (int k=0; k<36; ++k) acc = fmaf(pr[k], M3[k*112 + c], acc);
  out[t*112 + c] = acc;
}

extern "C" void kernel_launch(void* const* d_in, const int* in_sizes, int n_in,
                              void* d_out, int out_size, void* d_ws, size_t ws_size,
                              hipStream_t stream){
  const float* x    = (const float*)d_in[0];
  const int*   ei   = (const int*)d_in[1];
  const int*   batch= (const int*)d_in[2];
  const float* We   = (const float*)d_in[3];
  const float* be   = (const float*)d_in[4];
  const float* Wg   = (const float*)d_in[5];
  const float* a_sg = (const float*)d_in[6];
  const float* a_dg = (const float*)d_in[7];
  const float* bg   = (const float*)d_in[8];
  const float* gam  = (const float*)d_in[9];
  const float* bet  = (const float*)d_in[10];
  const float* W3   = (const float*)d_in[11];
  const float* a_s3 = (const float*)d_in[12];
  const float* a_d3 = (const float*)d_in[13];
  const float* b3   = (const float*)d_in[14];
  const float* gam3 = (const float*)d_in[15];
  const float* bet3 = (const float*)d_in[16];
  const float* M1   = (const float*)d_in[17];
  const float* bm1  = (const float*)d_in[18];
  const float* gm1  = (const float*)d_in[19];
  const float* bb1  = (const float*)d_in[20];
  const float* M2   = (const float*)d_in[21];
  const float* bm2  = (const float*)d_in[22];
  const float* gm2  = (const float*)d_in[23];
  const float* bb2  = (const float*)d_in[24];
  const float* M3   = (const float*)d_in[25];
  const float* bm3  = (const float*)d_in[26];
  float* out = (float*)d_out;

  char* ws = (char*)d_ws;
  size_t off = 0;
  auto alloc = [&](size_t bytes)->char*{
    char* p = ws + off; off += (bytes + 255) & ~(size_t)255; return p;
  };
  unsigned short* hAb = (unsigned short*)alloc((size_t)N_NODESC*DIM*2);
  unsigned short* hp  = (unsigned short*)alloc((size_t)N_NODESC*DIM*2);
  float* al_s   = (float*)alloc((size_t)N_NODESC*8*4);
  float* al_d   = (float*)alloc((size_t)N_NODESC*8*4);
  float* esc    = (float*)alloc((size_t)E_TOT*8*4);
  unsigned short* wN = (unsigned short*)alloc((size_t)E_TOT*8*2);
  int* row_ptr  = (int*)alloc((size_t)(N_NODESC+1)*4);
  int* deg      = (int*)alloc((size_t)N_NODESC*4);
  int* cursor   = (int*)alloc((size_t)N_NODESC*4);
  int* scanned  = (int*)alloc((size_t)N_NODESC*4);
  int* bsum     = (int*)alloc((size_t)SCAN_NB*4);
  int* col      = (int*)alloc((size_t)E_TOT*4);
  float* bns4   = (float*)alloc(4*2*DIM*4);
  float* partials = (float*)alloc((size_t)BNS_GRID*288*4);
  float* psum   = (float*)alloc((size_t)NGRAPH*DIM*4);
  int* pcnt     = (int*)alloc(NGRAPH*4);
  float* h1buf  = (float*)alloc((size_t)NGRAPH*72*4);
  float* h2buf  = (float*)alloc((size_t)NGRAPH*36*4);
  unsigned short* Wt = (unsigned short*)alloc((size_t)160*168*2);
  float* bias2  = (float*)alloc(160*4);
  (void)ws_size; (void)n_in; (void)in_sizes; (void)out_size;

  const int GEMM_GRID = (N_NODESC + 63)/64;   // 782

  // CSR build
  hipMemsetAsync(deg, 0, (size_t)N_NODESC*4, stream);
  k_count<<<(E_TOT+255)/256, 256, 0, stream>>>(ei, deg);
  k_scan1<<<SCAN_NB, 256, 0, stream>>>(deg, scanned, bsum);
  k_scan2<<<1, 128, 0, stream>>>(bsum);
  k_scan3<<<(N_NODESC+255)/256, 256, 0, stream>>>(scanned, bsum, row_ptr, cursor);
  k_scatter<<<(E_TOT+255)/256, 256, 0, stream>>>(ei, cursor, col);

  // embed: hAb = bf16(x) @ We + be  (MFMA, LDS Wt, fused f32->bf16 A-load)
  k_prep_w<<<144, 192, 0, stream>>>(We, be, nullptr, nullptr,
                                    nullptr, nullptr, nullptr, Wt, bias2, 128, 136, 0);
  k_mfma_gemm<9,4,136,144,1><<<GEMM_GRID, 256, 0, stream>>>(
      x, Wt, bias2, hAb, nullptr, nullptr, 128, 0);

  for (int L=0; L<4; ++L){
    const float* W  = (L<3) ? (Wg  + (size_t)L*DIM*DIM) : W3;
    const float* as = (L<3) ? (a_sg + (size_t)L*8*18)   : a_s3;
    const float* ad = (L<3) ? (a_dg + (size_t)L*8*18)   : a_d3;
    const float* bb = (L<3) ? (bg  + L*DIM) : b3;
    int H = (L<3) ? 8 : 1;
    int C = (L<3) ? 18 : 144;
    const float* bnp = (L==0) ? nullptr : bns4 + (size_t)(L-1)*2*DIM;
    const float* gmp = (L==0) ? nullptr : gam + (size_t)(L-1)*DIM;
    const float* btp = (L==0) ? nullptr : bet + (size_t)(L-1)*DIM;
    // BN folded into weights; attn logits folded as 16 extra output columns
    k_prep_w<<<160, 192, 0, stream>>>(W, nullptr, as, ad,
                                      bnp, gmp, btp, Wt, bias2, 144, 168, H);
    k_mfma_gemm<10,5,168,160,0><<<GEMM_GRID, 256, 0, stream>>>(
        hAb, Wt, bias2, hp, al_s, al_d, 144, H);
    k_edge_softmax<<<(N_NODESC*H+255)/256, 256, 0, stream>>>(
        al_s, al_d, row_ptr, col, esc, wN, H);
    k_aggregate2<<<(N_NODESC*36+255)/256, 256, 0, stream>>>(
        (const uint2*)hp, wN, row_ptr, col, bb, (uint2*)hAb, H, C/2);
    k_bnstats1<<<BNS_GRID, 256, 0, stream>>>((const uint2*)hAb, partials);
    k_bnstats2<<<288, 64, 0, stream>>>(partials, bns4 + (size_t)L*2*DIM);
  }

  hipMemsetAsync(psum, 0, (size_t)NGRAPH*DIM*4, stream);
  k_pool<<<NGRAPH*32, 128, 0, stream>>>((const unsigned*)hAb, batch, psum, pcnt);
  k_mlp1<<<72, 64, 0, stream>>>(psum, pcnt, bns4 + 3*2*DIM, gam3, bet3,
                                M1, bm1, gm1, bb1, h1buf);
  k_mlp2<<<36, 64, 0, stream>>>(h1buf, M2, bm2, gm2, bb2, h2buf);
  k_mlp3<<<112, 64, 0, stream>>>(h2buf, M3, bm3, out);
}

// Round 17
// 643.553 us; speedup vs baseline: 1.0611x; 1.0611x over previous
//
#include <hip/hip_runtime.h>
#include <cstdint>

#define N_NODESC 50000
#define N_EDGESC 500000
#define E_TOT    550000
#define DIM      144
#define NGRAPH   64
#define EPSV     1e-5f
#define SCAN_NB  ((N_NODESC + 511)/512)

typedef __attribute__((ext_vector_type(8))) short bf16x8;
typedef __attribute__((ext_vector_type(4))) float f32x4;

__device__ __forceinline__ float lrelu(float x){ return x > 0.f ? x : 0.2f*x; }

__device__ __forceinline__ unsigned short f2bf(float f){
  unsigned u = __float_as_uint(f);
  u += 0x7FFF + ((u >> 16) & 1);
  return (unsigned short)(u >> 16);
}
__device__ __forceinline__ float bf2f(unsigned short b){
  return __uint_as_float(((unsigned)b) << 16);
}

// ---------------- CSR build (by dst, self-loops appended) ----------------
__global__ void k_count(const int* __restrict__ ei, int* __restrict__ deg){
  int e = blockIdx.x*blockDim.x + threadIdx.x;
  if (e >= E_TOT) return;
  int d = (e < N_EDGESC) ? ei[N_EDGESC + e] : (e - N_EDGESC);
  atomicAdd(&deg[d], 1);
}

__global__ __launch_bounds__(256) void k_scan1(const int* __restrict__ deg,
    int* __restrict__ scanned, int* __restrict__ bsum){
  __shared__ int ls[256];
  int b = blockIdx.x, t = threadIdx.x;
  int i0 = b*512 + 2*t;
  int e0 = (i0   < N_NODESC) ? deg[i0]   : 0;
  int e1 = (i0+1 < N_NODESC) ? deg[i0+1] : 0;
  int s = e0 + e1;
  ls[t] = s;
  __syncthreads();
  #pragma unroll
  for (int ofs=1; ofs<256; ofs<<=1){
    int v = (t >= ofs) ? ls[t-ofs] : 0;
    __syncthreads();
    ls[t] += v;
    __syncthreads();
  }
  int excl = ls[t] - s;
  if (i0   < N_NODESC) scanned[i0]   = excl;
  if (i0+1 < N_NODESC) scanned[i0+1] = excl + e0;
  if (t == 255) bsum[b] = ls[255];
}

__global__ void k_scan2(int* __restrict__ bsum){
  __shared__ int ls[128];
  int t = threadIdx.x;
  int v = (t < SCAN_NB) ? bsum[t] : 0;
  ls[t] = v;
  __syncthreads();
  #pragma unroll
  for (int ofs=1; ofs<128; ofs<<=1){
    int u = (t >= ofs) ? ls[t-ofs] : 0;
    __syncthreads();
    ls[t] += u;
    __syncthreads();
  }
  if (t < SCAN_NB) bsum[t] = ls[t] - v;
}

__global__ __launch_bounds__(256) void k_scan3(const int* __restrict__ scanned,
    const int* __restrict__ bsum, int* __restrict__ row_ptr, int* __restrict__ cursor){
  int i = blockIdx.x*blockDim.x + threadIdx.x;
  if (i < N_NODESC){
    int v = scanned[i] + bsum[i >> 9];
    row_ptr[i] = v; cursor[i] = v;
  }
  if (i == 0) row_ptr[N_NODESC] = E_TOT;
}

__global__ void k_scatter(const int* __restrict__ ei, int* __restrict__ cursor,
                          int* __restrict__ col){
  int e = blockIdx.x*blockDim.x + threadIdx.x;
  if (e >= E_TOT) return;
  int s, d;
  if (e < N_EDGESC){ s = ei[e]; d = ei[N_EDGESC + e]; } else { s = e - N_EDGESC; d = s; }
  int pos = atomicAdd(&cursor[d], 1);
  col[pos] = s;
}

// ---------------- weight prep: W'' = diag(sc)*W (+attn-logit cols), bf16, transposed ----------------
__global__ __launch_bounds__(192) void k_prep_w(
    const float* __restrict__ W, const float* __restrict__ bias_in,
    const float* __restrict__ a_s, const float* __restrict__ a_d,
    const float* __restrict__ bnsum, const float* __restrict__ bngam,
    const float* __restrict__ bnbet,
    unsigned short* __restrict__ Wt, float* __restrict__ bias2,
    int K, int SK, int H){
  __shared__ float red[256];
  int np = blockIdx.x, k = threadIdx.x;
  float sc = 1.f, sh = 0.f;
  if (k < K && bnsum){
    float mu  = bnsum[k] * (1.f/N_NODESC);
    float var = bnsum[K+k] * (1.f/N_NODESC) - mu*mu;
    float inv = rsqrtf(var + EPSV);
    sc = inv * bngam[k];
    sh = bnbet[k] - mu*sc;
  }
  float wcomb = 0.f;
  if (k < K){
    if (np < 144) wcomb = W[(size_t)k*144 + np];
    else if (H > 0){
      int c = np - 144;
      bool iss = c < 8;
      int h = iss ? c : c - 8;
      if (h < H){
        const float* av = iss ? a_s : a_d;
        int C = 144 / H;
        for (int j=0;j<C;++j) wcomb += W[(size_t)k*144 + h*C + j] * av[h*C + j];
      }
    }
  }
  if (k < SK) Wt[(size_t)np*SK + k] = f2bf(wcomb*sc);
  red[k] = (k < K) ? sh*wcomb : 0.f;
  if (k < 64) red[k+192] = 0.f;
  __syncthreads();
  #pragma unroll
  for (int s=128; s>0; s>>=1){
    if (k < s) red[k] += red[k+s];
    __syncthreads();
  }
  if (k == 0){
    float b = red[0];
    if (np < 144 && bias_in) b += bias_in[np];
    bias2[np] = b;
  }
}

// ---------------- MFMA GEMM with LDS-staged Wt; optional f32 A (fused cast) ----------------
template<int NT, int KS, int SK, int NROW, int AF32>
__global__ __launch_bounds__(256) void k_mfma_gemm(
    const void* __restrict__ Av,
    const unsigned short* __restrict__ Wt,
    const float* __restrict__ bias2,
    unsigned short* __restrict__ hp,
    float* __restrict__ al_s, float* __restrict__ al_d,
    int KA, int H){
  __shared__ unsigned short sW[NROW*SK];
  int t = threadIdx.x;
  for (int i = t; i < NROW*SK/8; i += 256)
    ((uint4*)sW)[i] = ((const uint4*)Wt)[i];
  __syncthreads();

  int wave = t >> 6, lane = t & 63;
  int c = lane & 15, quad = lane >> 4;
  int m_base = blockIdx.x*64 + wave*16;
  int mA = m_base + c; if (mA > N_NODESC-1) mA = N_NODESC-1;
  f32x4 acc[NT];
  #pragma unroll
  for (int i=0;i<NT;++i) acc[i] = (f32x4){0.f,0.f,0.f,0.f};
  #pragma unroll
  for (int ks=0; ks<KS; ++ks){
    bf16x8 af;
    if (AF32){
      const float* Arow = (const float*)Av + (size_t)mA*KA + quad*8;
      float4 f0 = *(const float4*)(Arow + ks*32);
      float4 f1 = *(const float4*)(Arow + ks*32 + 4);
      unsigned short tmp[8] = { f2bf(f0.x),f2bf(f0.y),f2bf(f0.z),f2bf(f0.w),
                                f2bf(f1.x),f2bf(f1.y),f2bf(f1.z),f2bf(f1.w) };
      af = *(const bf16x8*)tmp;
    } else {
      const unsigned short* Arow = (const unsigned short*)Av + (size_t)mA*KA + quad*8;
      af = *(const bf16x8*)(Arow + ks*32);
    }
    #pragma unroll
    for (int tt=0; tt<NT; ++tt){
      bf16x8 bfr = *(const bf16x8*)(sW + (tt*16 + c)*SK + ks*32 + quad*8);
      acc[tt] = __builtin_amdgcn_mfma_f32_16x16x32_bf16(af, bfr, acc[tt], 0, 0, 0);
    }
  }
  #pragma unroll
  for (int tt=0; tt<NT; ++tt){
    int n = tt*16 + c;
    float b = bias2[n];
    #pragma unroll
    for (int r=0;r<4;++r){
      int m = m_base + quad*4 + r;
      if (m < N_NODESC){
        float v = acc[tt][r] + b;
        if (n < 144){
          hp[(size_t)m*144 + n] = f2bf(v);
        } else {
          int cc = n - 144;
          if (cc < 8){ if (cc < H) al_s[m*H + cc] = v; }
          else { int h = cc - 8; if (h < H) al_d[m*H + h] = v; }
        }
      }
    }
  }
}

// ---------------- segment softmax: online pass -> fully normalized f32 weights ----------------
// Pass: gather scores -> esc raw, online max+den. Final loop (L2-warm, own data):
// esc <- exp(sc - m) / den  — aggregate needs no den and no divide.
#define EB 8
__global__ __launch_bounds__(256) void k_edge_softmax(
    const float* __restrict__ al_s, const float* __restrict__ al_d,
    const int* __restrict__ row_ptr, const int* __restrict__ col,
    float* __restrict__ esc, int H){
  int idx = blockIdx.x*blockDim.x + threadIdx.x;
  if (idx >= N_NODESC*H) return;
  int n = idx / H, h = idx - n*H;
  int p0 = row_ptr[n], p1 = row_ptr[n+1];
  float ald = al_d[idx];
  float m = -3.4e38f, d = 0.f;
  for (int base = p0; base < p1; base += EB){
    int cnt = min(EB, p1 - base);
    int ss[EB];
    #pragma unroll
    for (int i=0;i<EB;++i) if (i<cnt) ss[i] = col[base+i];
    float sc[EB];
    #pragma unroll
    for (int i=0;i<EB;++i) if (i<cnt) sc[i] = lrelu(al_s[ss[i]*H + h] + ald);
    float bm = -3.4e38f;
    #pragma unroll
    for (int i=0;i<EB;++i) if (i<cnt){
      esc[(size_t)(base+i)*H + h] = sc[i];
      bm = fmaxf(bm, sc[i]);
    }
    if (bm > m){ d *= __expf(m - bm); m = bm; }
    #pragma unroll
    for (int i=0;i<EB;++i) if (i<cnt) d += __expf(sc[i] - m);
  }
  float inv = 1.f/(d + 1e-16f);
  for (int e = p0; e < p1; ++e)
    esc[(size_t)e*H + h] = __expf(esc[(size_t)e*H + h] - m) * inv;
}

// ---------------- weighted gather (batched prefetch); w fully normalized f32 ----------------
// 72 threads/node, 4-byte hp loads — the proven R15 operating point.
__global__ __launch_bounds__(256) void k_aggregate2(
    const unsigned* __restrict__ hp2, const float* __restrict__ w,
    const int* __restrict__ row_ptr, const int* __restrict__ col,
    const float* __restrict__ bias, unsigned* __restrict__ out,
    int H, int C2){
  int idx = blockIdx.x*blockDim.x + threadIdx.x;
  if (idx >= N_NODESC*72) return;
  int n = idx / 72, cp = idx - n*72;
  int h = cp / C2;
  int p0 = row_ptr[n], p1 = row_ptr[n+1];
  float a0 = 0.f, a1 = 0.f;
  for (int base = p0; base < p1; base += EB){
    int cnt = min(EB, p1 - base);
    int ss[EB]; float ww[EB];
    #pragma unroll
    for (int i=0;i<EB;++i) if (i<cnt){
      ss[i] = col[base+i];
      ww[i] = w[(size_t)(base+i)*H + h];
    }
    unsigned vv[EB];
    #pragma unroll
    for (int i=0;i<EB;++i) if (i<cnt) vv[i] = hp2[(size_t)ss[i]*72 + cp];
    #pragma unroll
    for (int i=0;i<EB;++i) if (i<cnt){
      a0 = fmaf(ww[i], __uint_as_float(vv[i] << 16), a0);
      a1 = fmaf(ww[i], __uint_as_float(vv[i] & 0xFFFF0000u), a1);
    }
  }
  int c0 = 2*cp;
  float r0 = fmaxf(a0 + bias[c0],   0.f);
  float r1 = fmaxf(a1 + bias[c0+1], 0.f);
  out[(size_t)n*72 + cp] = (unsigned)f2bf(r0) | ((unsigned)f2bf(r1) << 16);
}

// ---------------- batchnorm stats: two-stage, atomic-free ----------------
#define BNS_GRID 512
__global__ __launch_bounds__(256) void k_bnstats1(const uint2* __restrict__ h4,
                                                  float* __restrict__ partials){
  __shared__ float red[252*8];
  int t = threadIdx.x;
  int r = t / 36, c = t - r*36;
  bool active = (t < 252);
  int rows = (N_NODESC + BNS_GRID - 1)/BNS_GRID;
  int n0 = blockIdx.x*rows, n1 = min(N_NODESC, n0+rows);
  float s[4] = {0,0,0,0}, q[4] = {0,0,0,0};
  if (active){
    for (int n = n0 + r; n < n1; n += 7){
      uint2 v = h4[(size_t)n*36 + c];
      float f0 = __uint_as_float(v.x << 16);
      float f1 = __uint_as_float(v.x & 0xFFFF0000u);
      float f2 = __uint_as_float(v.y << 16);
      float f3 = __uint_as_float(v.y & 0xFFFF0000u);
      s[0]+=f0; q[0]+=f0*f0; s[1]+=f1; q[1]+=f1*f1;
      s[2]+=f2; q[2]+=f2*f2; s[3]+=f3; q[3]+=f3*f3;
    }
    #pragma unroll
    for (int j=0;j<4;++j){
      red[(c*7+r)*8 + j]     = s[j];
      red[(c*7+r)*8 + 4 + j] = q[j];
    }
  }
  __syncthreads();
  if (t < 36){
    float ss[4]={0,0,0,0}, qq[4]={0,0,0,0};
    for (int rr=0; rr<7; ++rr){
      #pragma unroll
      for (int j=0;j<4;++j){
        ss[j] += red[(t*7+rr)*8 + j];
        qq[j] += red[(t*7+rr)*8 + 4 + j];
      }
    }
    float* p = partials + (size_t)blockIdx.x*288;
    #pragma unroll
    for (int j=0;j<4;++j){
      p[4*t+j]       = ss[j];
      p[144+4*t+j]   = qq[j];
    }
  }
}

__global__ __launch_bounds__(64) void k_bnstats2(const float* __restrict__ partials,
                                                 float* __restrict__ sums){
  int i = blockIdx.x, t = threadIdx.x;
  float s = 0.f;
  for (int b = t; b < BNS_GRID; b += 64) s += partials[(size_t)b*288 + i];
  #pragma unroll
  for (int o=32; o>0; o>>=1) s += __shfl_xor(s, o, 64);
  if (t == 0) sums[i] = s;
}

// ---------------- per-graph mean pool over bf16 hA (32 parts/graph) ----------------
__device__ int lbound(const int* a, int n, int v){
  int lo = 0, hi = n;
  while (lo < hi){ int m = (lo+hi) >> 1; if (a[m] < v) lo = m+1; else hi = m; }
  return lo;
}

__global__ __launch_bounds__(128) void k_pool(const unsigned* __restrict__ h2,
    const int* __restrict__ batch, float* __restrict__ sums, int* __restrict__ cnts){
  int g = blockIdx.x & 63, part = blockIdx.x >> 6;
  __shared__ int sb[2];
  if (threadIdx.x == 0){ sb[0] = lbound(batch, N_NODESC, g); sb[1] = lbound(batch, N_NODESC, g+1); }
  __syncthreads();
  int lo = sb[0], hi = sb[1];
  int t = threadIdx.x;
  if (t < 72){
    float a0 = 0.f, a1 = 0.f;
    for (int n = lo + part; n < hi; n += 32){
      unsigned v = h2[(size_t)n*72 + t];
      a0 += __uint_as_float(v << 16);
      a1 += __uint_as_float(v & 0xFFFF0000u);
    }
    atomicAdd(&sums[g*DIM + 2*t],   a0);
    atomicAdd(&sums[g*DIM + 2*t+1], a1);
  }
  if (t == 0 && part == 0) cnts[g] = hi - lo;
}

// ---------------- MLP head: column-parallel, BN via wave reduction ----------------
__global__ __launch_bounds__(64) void k_mlp1(const float* __restrict__ psum,
    const int* __restrict__ cnts,
    const float* __restrict__ bn3, const float* __restrict__ gam3,
    const float* __restrict__ bet3,
    const float* __restrict__ M1, const float* __restrict__ bm1,
    const float* __restrict__ gm1, const float* __restrict__ bb1,
    float* __restrict__ h1){
  __shared__ float sSc[144], sSh[144];
  int t = threadIdx.x, c = blockIdx.x;
  for (int i=t; i<144; i+=64){
    float mu  = bn3[i] * (1.f/N_NODESC);
    float var = bn3[144+i] * (1.f/N_NODESC) - mu*mu;
    float sc  = rsqrtf(var + EPSV) * gam3[i];
    sSc[i] = sc; sSh[i] = bet3[i] - mu*sc;
  }
  __syncthreads();
  float invc = 1.f / (float)max(cnts[t], 1);
  float acc = bm1[c];
  const float* pr = psum + t*144;
  for (int k=0; k<144; ++k){
    float g = fmaf(pr[k]*invc, sSc[k], sSh[k]);
    acc = fmaf(g, M1[k*72 + c], acc);
  }
  float s = acc, q = acc*acc;
  #pragma unroll
  for (int o=32; o>0; o>>=1){ s += __shfl_xor(s, o, 64); q += __shfl_xor(q, o, 64); }
  float mu = s*(1.f/64.f), var = q*(1.f/64.f) - mu*mu;
  float v = (acc - mu)*rsqrtf(var + EPSV)*gm1[c] + bb1[c];
  h1[t*72 + c] = fmaxf(v, 0.f);
}

__global__ __launch_bounds__(64) void k_mlp2(const float* __restrict__ h1,
    const float* __restrict__ M2, const float* __restrict__ bm2,
    const float* __restrict__ gm2, const float* __restrict__ bb2,
    float* __restrict__ h2){
  int t = threadIdx.x, c = blockIdx.x;
  float acc = bm2[c];
  const float* pr = h1 + t*72;
  for (int k=0; k<72; ++k) acc = fmaf(pr[k], M2[k*36 + c], acc);
  float s = acc, q = acc*acc;
  #pragma unroll
  for (int o=32; o>0; o>>=1){ s += __shfl_xor(s, o, 64); q += __shfl_xor(q, o, 64); }
  float mu = s*(1.f/64.f), var = q*(1.f/64.f) - mu*mu;
  float v = (acc - mu)*rsqrtf(var + EPSV)*gm2[c] + bb2[c];
  h2[t*36 + c] = fmaxf(v, 0.f);
}

__global__ __launch_bounds__(64) void k_mlp3(const float* __restrict__ h2,
    const float* __restrict__ M3, const float* __restrict__ bm3,
    float* __restrict__ out){
  int t = threadIdx.x, c = blockIdx.x;
  float acc = bm3[c];
  const float* pr = h2 + t*36;
  for (int k=0; k<36; ++k) acc = fmaf(pr[k], M3[k*112 + c], acc);
  out[t*112 + c] = acc;
}

extern "C" void kernel_launch(void* const* d_in, const int* in_sizes, int n_in,
                              void* d_out, int out_size, void* d_ws, size_t ws_size,
                              hipStream_t stream){
  const float* x    = (const float*)d_in[0];
  const int*   ei   = (const int*)d_in[1];
  const int*   batch= (const int*)d_in[2];
  const float* We   = (const float*)d_in[3];
  const float* be   = (const float*)d_in[4];
  const float* Wg   = (const float*)d_in[5];
  const float* a_sg = (const float*)d_in[6];
  const float* a_dg = (const float*)d_in[7];
  const float* bg   = (const float*)d_in[8];
  const float* gam  = (const float*)d_in[9];
  const float* bet  = (const float*)d_in[10];
  const float* W3   = (const float*)d_in[11];
  const float* a_s3 = (const float*)d_in[12];
  const float* a_d3 = (const float*)d_in[13];
  const float* b3   = (const float*)d_in[14];
  const float* gam3 = (const float*)d_in[15];
  const float* bet3 = (const float*)d_in[16];
  const float* M1   = (const float*)d_in[17];
  const float* bm1  = (const float*)d_in[18];
  const float* gm1  = (const float*)d_in[19];
  const float* bb1  = (const float*)d_in[20];
  const float* M2   = (const float*)d_in[21];
  const float* bm2  = (const float*)d_in[22];
  const float* gm2  = (const float*)d_in[23];
  const float* bb2  = (const float*)d_in[24];
  const float* M3   = (const float*)d_in[25];
  const float* bm3  = (const float*)d_in[26];
  float* out = (float*)d_out;

  char* ws = (char*)d_ws;
  size_t off = 0;
  auto alloc = [&](size_t bytes)->char*{
    char* p = ws + off; off += (bytes + 255) & ~(size_t)255; return p;
  };
  unsigned short* hAb = (unsigned short*)alloc((size_t)N_NODESC*DIM*2);
  unsigned short* hp  = (unsigned short*)alloc((size_t)N_NODESC*DIM*2);
  float* al_s   = (float*)alloc((size_t)N_NODESC*8*4);
  float* al_d   = (float*)alloc((size_t)N_NODESC*8*4);
  float* esc    = (float*)alloc((size_t)E_TOT*8*4);
  int* row_ptr  = (int*)alloc((size_t)(N_NODESC+1)*4);
  int* deg      = (int*)alloc((size_t)N_NODESC*4);
  int* cursor   = (int*)alloc((size_t)N_NODESC*4);
  int* scanned  = (int*)alloc((size_t)N_NODESC*4);
  int* bsum     = (int*)alloc((size_t)SCAN_NB*4);
  int* col      = (int*)alloc((size_t)E_TOT*4);
  float* bns4   = (float*)alloc(4*2*DIM*4);
  float* partials = (float*)alloc((size_t)BNS_GRID*288*4);
  float* psum   = (float*)alloc((size_t)NGRAPH*DIM*4);
  int* pcnt     = (int*)alloc(NGRAPH*4);
  float* h1buf  = (float*)alloc((size_t)NGRAPH*72*4);
  float* h2buf  = (float*)alloc((size_t)NGRAPH*36*4);
  unsigned short* Wt = (unsigned short*)alloc((size_t)160*168*2);
  float* bias2  = (float*)alloc(160*4);
  (void)ws_size; (void)n_in; (void)in_sizes; (void)out_size;

  const int GEMM_GRID = (N_NODESC + 63)/64;   // 782

  // CSR build
  hipMemsetAsync(deg, 0, (size_t)N_NODESC*4, stream);
  k_count<<<(E_TOT+255)/256, 256, 0, stream>>>(ei, deg);
  k_scan1<<<SCAN_NB, 256, 0, stream>>>(deg, scanned, bsum);
  k_scan2<<<1, 128, 0, stream>>>(bsum);
  k_scan3<<<(N_NODESC+255)/256, 256, 0, stream>>>(scanned, bsum, row_ptr, cursor);
  k_scatter<<<(E_TOT+255)/256, 256, 0, stream>>>(ei, cursor, col);

  // embed: hAb = bf16(x) @ We + be  (MFMA, LDS Wt, fused f32->bf16 A-load)
  k_prep_w<<<144, 192, 0, stream>>>(We, be, nullptr, nullptr,
                                    nullptr, nullptr, nullptr, Wt, bias2, 128, 136, 0);
  k_mfma_gemm<9,4,136,144,1><<<GEMM_GRID, 256, 0, stream>>>(
      x, Wt, bias2, hAb, nullptr, nullptr, 128, 0);

  for (int L=0; L<4; ++L){
    const float* W  = (L<3) ? (Wg  + (size_t)L*DIM*DIM) : W3;
    const float* as = (L<3) ? (a_sg + (size_t)L*8*18)   : a_s3;
    const float* ad = (L<3) ? (a_dg + (size_t)L*8*18)   : a_d3;
    const float* bb = (L<3) ? (bg  + L*DIM) : b3;
    int H = (L<3) ? 8 : 1;
    int C = (L<3) ? 18 : 144;
    const float* bnp = (L==0) ? nullptr : bns4 + (size_t)(L-1)*2*DIM;
    const float* gmp = (L==0) ? nullptr : gam + (size_t)(L-1)*DIM;
    const float* btp = (L==0) ? nullptr : bet + (size_t)(L-1)*DIM;
    // BN folded into weights; attn logits folded as 16 extra output columns
    k_prep_w<<<160, 192, 0, stream>>>(W, nullptr, as, ad,
                                      bnp, gmp, btp, Wt, bias2, 144, 168, H);
    k_mfma_gemm<10,5,168,160,0><<<GEMM_GRID, 256, 0, stream>>>(
        hAb, Wt, bias2, hp, al_s, al_d, 144, H);
    k_edge_softmax<<<(N_NODESC*H+255)/256, 256, 0, stream>>>(
        al_s, al_d, row_ptr, col, esc, H);
    k_aggregate2<<<(N_NODESC*72+255)/256, 256, 0, stream>>>(
        (const unsigned*)hp, esc, row_ptr, col, bb, (unsigned*)hAb, H, C/2);
    k_bnstats1<<<BNS_GRID, 256, 0, stream>>>((const uint2*)hAb, partials);
    k_bnstats2<<<288, 64, 0, stream>>>(partials, bns4 + (size_t)L*2*DIM);
  }

  hipMemsetAsync(psum, 0, (size_t)NGRAPH*DIM*4, stream);
  k_pool<<<NGRAPH*32, 128, 0, stream>>>((const unsigned*)hAb, batch, psum, pcnt);
  k_mlp1<<<72, 64, 0, stream>>>(psum, pcnt, bns4 + 3*2*DIM, gam3, bet3,
                                M1, bm1, gm1, bb1, h1buf);
  k_mlp2<<<36, 64, 0, stream>>>(h1buf, M2, bm2, gm2, bb2, h2buf);
  k_mlp3<<<112, 64, 0, stream>>>(h2buf, M3, bm3, out);
}

// Round 18
// 602.793 us; speedup vs baseline: 1.1328x; 1.0676x over previous
//
#include <hip/hip_runtime.h>
#include <cstdint>

#define N_NODESC 50000
#define N_EDGESC 500000
#define E_TOT    550000
#define DIM      144
#define NGRAPH   64
#define EPSV     1e-5f
#define SCAN_NB  ((N_NODESC + 511)/512)

typedef __attribute__((ext_vector_type(8))) short bf16x8;
typedef __attribute__((ext_vector_type(4))) float f32x4;

__device__ __forceinline__ float lrelu(float x){ return x > 0.f ? x : 0.2f*x; }

__device__ __forceinline__ unsigned short f2bf(float f){
  unsigned u = __float_as_uint(f);
  u += 0x7FFF + ((u >> 16) & 1);
  return (unsigned short)(u >> 16);
}
__device__ __forceinline__ float bf2f(unsigned short b){
  return __uint_as_float(((unsigned)b) << 16);
}

// ---------------- CSR build (by dst, self-loops appended) ----------------
__global__ void k_count(const int* __restrict__ ei, int* __restrict__ deg){
  int e = blockIdx.x*blockDim.x + threadIdx.x;
  if (e >= E_TOT) return;
  int d = (e < N_EDGESC) ? ei[N_EDGESC + e] : (e - N_EDGESC);
  atomicAdd(&deg[d], 1);
}

__global__ __launch_bounds__(256) void k_scan1(const int* __restrict__ deg,
    int* __restrict__ scanned, int* __restrict__ bsum){
  __shared__ int ls[256];
  int b = blockIdx.x, t = threadIdx.x;
  int i0 = b*512 + 2*t;
  int e0 = (i0   < N_NODESC) ? deg[i0]   : 0;
  int e1 = (i0+1 < N_NODESC) ? deg[i0+1] : 0;
  int s = e0 + e1;
  ls[t] = s;
  __syncthreads();
  #pragma unroll
  for (int ofs=1; ofs<256; ofs<<=1){
    int v = (t >= ofs) ? ls[t-ofs] : 0;
    __syncthreads();
    ls[t] += v;
    __syncthreads();
  }
  int excl = ls[t] - s;
  if (i0   < N_NODESC) scanned[i0]   = excl;
  if (i0+1 < N_NODESC) scanned[i0+1] = excl + e0;
  if (t == 255) bsum[b] = ls[255];
}

__global__ void k_scan2(int* __restrict__ bsum){
  __shared__ int ls[128];
  int t = threadIdx.x;
  int v = (t < SCAN_NB) ? bsum[t] : 0;
  ls[t] = v;
  __syncthreads();
  #pragma unroll
  for (int ofs=1; ofs<128; ofs<<=1){
    int u = (t >= ofs) ? ls[t-ofs] : 0;
    __syncthreads();
    ls[t] += u;
    __syncthreads();
  }
  if (t < SCAN_NB) bsum[t] = ls[t] - v;
}

__global__ __launch_bounds__(256) void k_scan3(const int* __restrict__ scanned,
    const int* __restrict__ bsum, int* __restrict__ row_ptr, int* __restrict__ cursor){
  int i = blockIdx.x*blockDim.x + threadIdx.x;
  if (i < N_NODESC){
    int v = scanned[i] + bsum[i >> 9];
    row_ptr[i] = v; cursor[i] = v;
  }
  if (i == 0) row_ptr[N_NODESC] = E_TOT;
}

__global__ void k_scatter(const int* __restrict__ ei, int* __restrict__ cursor,
                          int* __restrict__ col){
  int e = blockIdx.x*blockDim.x + threadIdx.x;
  if (e >= E_TOT) return;
  int s, d;
  if (e < N_EDGESC){ s = ei[e]; d = ei[N_EDGESC + e]; } else { s = e - N_EDGESC; d = s; }
  int pos = atomicAdd(&cursor[d], 1);
  col[pos] = s;
}

// ---------------- weight prep: W'' = diag(sc)*W (+attn-logit cols), bf16, transposed ----------------
__global__ __launch_bounds__(192) void k_prep_w(
    const float* __restrict__ W, const float* __restrict__ bias_in,
    const float* __restrict__ a_s, const float* __restrict__ a_d,
    const float* __restrict__ bnsum, const float* __restrict__ bngam,
    const float* __restrict__ bnbet,
    unsigned short* __restrict__ Wt, float* __restrict__ bias2,
    int K, int SK, int H){
  __shared__ float red[256];
  int np = blockIdx.x, k = threadIdx.x;
  float sc = 1.f, sh = 0.f;
  if (k < K && bnsum){
    float mu  = bnsum[k] * (1.f/N_NODESC);
    float var = bnsum[K+k] * (1.f/N_NODESC) - mu*mu;
    float inv = rsqrtf(var + EPSV);
    sc = inv * bngam[k];
    sh = bnbet[k] - mu*sc;
  }
  float wcomb = 0.f;
  if (k < K){
    if (np < 144) wcomb = W[(size_t)k*144 + np];
    else if (H > 0){
      int c = np - 144;
      bool iss = c < 8;
      int h = iss ? c : c - 8;
      if (h < H){
        const float* av = iss ? a_s : a_d;
        int C = 144 / H;
        for (int j=0;j<C;++j) wcomb += W[(size_t)k*144 + h*C + j] * av[h*C + j];
      }
    }
  }
  if (k < SK) Wt[(size_t)np*SK + k] = f2bf(wcomb*sc);
  red[k] = (k < K) ? sh*wcomb : 0.f;
  if (k < 64) red[k+192] = 0.f;
  __syncthreads();
  #pragma unroll
  for (int s=128; s>0; s>>=1){
    if (k < s) red[k] += red[k+s];
    __syncthreads();
  }
  if (k == 0){
    float b = red[0];
    if (np < 144 && bias_in) b += bias_in[np];
    bias2[np] = b;
  }
}

// ---------------- MFMA GEMM: LDS Wt, C restaged through LDS for uint4 stores ----------------
template<int NT, int KS, int SK, int NROW, int AF32>
__global__ __launch_bounds__(256) void k_mfma_gemm(
    const void* __restrict__ Av,
    const unsigned short* __restrict__ Wt,
    const float* __restrict__ bias2,
    unsigned short* __restrict__ hp,
    float* __restrict__ al_s, float* __restrict__ al_d,
    int KA, int H){
  __shared__ unsigned short sW[NROW*SK];
  int t = threadIdx.x;
  for (int i = t; i < NROW*SK/8; i += 256)
    ((uint4*)sW)[i] = ((const uint4*)Wt)[i];
  __syncthreads();

  int wave = t >> 6, lane = t & 63;
  int c = lane & 15, quad = lane >> 4;
  int m_base = blockIdx.x*64 + wave*16;
  int mA = m_base + c; if (mA > N_NODESC-1) mA = N_NODESC-1;
  f32x4 acc[NT];
  #pragma unroll
  for (int i=0;i<NT;++i) acc[i] = (f32x4){0.f,0.f,0.f,0.f};
  #pragma unroll
  for (int ks=0; ks<KS; ++ks){
    bf16x8 af;
    if (AF32){
      const float* Arow = (const float*)Av + (size_t)mA*KA + quad*8;
      float4 f0 = *(const float4*)(Arow + ks*32);
      float4 f1 = *(const float4*)(Arow + ks*32 + 4);
      unsigned short tmp[8] = { f2bf(f0.x),f2bf(f0.y),f2bf(f0.z),f2bf(f0.w),
                                f2bf(f1.x),f2bf(f1.y),f2bf(f1.z),f2bf(f1.w) };
      af = *(const bf16x8*)tmp;
    } else {
      const unsigned short* Arow = (const unsigned short*)Av + (size_t)mA*KA + quad*8;
      af = *(const bf16x8*)(Arow + ks*32);
    }
    #pragma unroll
    for (int tt=0; tt<NT; ++tt){
      bf16x8 bfr = *(const bf16x8*)(sW + (tt*16 + c)*SK + ks*32 + quad*8);
      acc[tt] = __builtin_amdgcn_mfma_f32_16x16x32_bf16(af, bfr, acc[tt], 0, 0, 0);
    }
  }

  // attn-logit columns (n>=144): direct scalar stores from registers
  if (NT > 9){
    int n = 144 + c;
    float b = bias2[n];
    #pragma unroll
    for (int r=0;r<4;++r){
      int m = m_base + quad*4 + r;
      if (m < N_NODESC){
        float v = acc[9][r] + b;
        if (c < 8){ if (c < H) al_s[m*H + c] = v; }
        else { int h = c - 8; if (h < H) al_d[m*H + h] = v; }
      }
    }
  }

  // restage 64x144 bf16 C tile through LDS (reuse sW; all reads done)
  __syncthreads();
  unsigned short* sOut = sW + wave*2304;   // 16 rows * 144 cols
  #pragma unroll
  for (int tt=0; tt<9; ++tt){
    int n = tt*16 + c;
    float b = bias2[n];
    #pragma unroll
    for (int r=0;r<4;++r)
      sOut[(quad*4+r)*144 + n] = f2bf(acc[tt][r] + b);
  }
  __syncthreads();
  int base_row = blockIdx.x*64;
  for (int i = t; i < 1152; i += 256){       // 64 rows * 18 uint4/row
    int rr = i/18, j = i - rr*18;
    int m = base_row + rr;
    if (m < N_NODESC)
      *((uint4*)(hp + (size_t)m*144) + j) = *((const uint4*)(sW + rr*144) + j);
  }
}

// ---------------- segment softmax: online max+den, then re-gather & emit weights ----------------
// No raw-score round-trip: pass 1 computes m,d only; pass 2 re-gathers the
// (now L2-warm) al_s values and writes normalized weights directly.
#define EB 8
__global__ __launch_bounds__(256) void k_edge_softmax(
    const float* __restrict__ al_s, const float* __restrict__ al_d,
    const int* __restrict__ row_ptr, const int* __restrict__ col,
    float* __restrict__ esc, int H){
  int idx = blockIdx.x*blockDim.x + threadIdx.x;
  if (idx >= N_NODESC*H) return;
  int n = idx / H, h = idx - n*H;
  int p0 = row_ptr[n], p1 = row_ptr[n+1];
  float ald = al_d[idx];
  float m = -3.4e38f, d = 0.f;
  for (int base = p0; base < p1; base += EB){
    int cnt = min(EB, p1 - base);
    int ss[EB];
    #pragma unroll
    for (int i=0;i<EB;++i) if (i<cnt) ss[i] = col[base+i];
    float sc[EB];
    #pragma unroll
    for (int i=0;i<EB;++i) if (i<cnt) sc[i] = lrelu(al_s[ss[i]*H + h] + ald);
    float bm = -3.4e38f;
    #pragma unroll
    for (int i=0;i<EB;++i) if (i<cnt) bm = fmaxf(bm, sc[i]);
    if (bm > m){ d *= __expf(m - bm); m = bm; }
    #pragma unroll
    for (int i=0;i<EB;++i) if (i<cnt) d += __expf(sc[i] - m);
  }
  float inv = 1.f/(d + 1e-16f);
  for (int base = p0; base < p1; base += EB){
    int cnt = min(EB, p1 - base);
    int ss[EB];
    #pragma unroll
    for (int i=0;i<EB;++i) if (i<cnt) ss[i] = col[base+i];
    float sc[EB];
    #pragma unroll
    for (int i=0;i<EB;++i) if (i<cnt) sc[i] = lrelu(al_s[ss[i]*H + h] + ald);
    #pragma unroll
    for (int i=0;i<EB;++i) if (i<cnt)
      esc[(size_t)(base+i)*H + h] = __expf(sc[i] - m) * inv;
  }
}

// ---------------- weighted gather (batched prefetch); w fully normalized f32 ----------------
__global__ __launch_bounds__(256) void k_aggregate2(
    const unsigned* __restrict__ hp2, const float* __restrict__ w,
    const int* __restrict__ row_ptr, const int* __restrict__ col,
    const float* __restrict__ bias, unsigned* __restrict__ out,
    int H, int C2){
  int idx = blockIdx.x*blockDim.x + threadIdx.x;
  if (idx >= N_NODESC*72) return;
  int n = idx / 72, cp = idx - n*72;
  int h = cp / C2;
  int p0 = row_ptr[n], p1 = row_ptr[n+1];
  float a0 = 0.f, a1 = 0.f;
  for (int base = p0; base < p1; base += EB){
    int cnt = min(EB, p1 - base);
    int ss[EB]; float ww[EB];
    #pragma unroll
    for (int i=0;i<EB;++i) if (i<cnt){
      ss[i] = col[base+i];
      ww[i] = w[(size_t)(base+i)*H + h];
    }
    unsigned vv[EB];
    #pragma unroll
    for (int i=0;i<EB;++i) if (i<cnt) vv[i] = hp2[(size_t)ss[i]*72 + cp];
    #pragma unroll
    for (int i=0;i<EB;++i) if (i<cnt){
      a0 = fmaf(ww[i], __uint_as_float(vv[i] << 16), a0);
      a1 = fmaf(ww[i], __uint_as_float(vv[i] & 0xFFFF0000u), a1);
    }
  }
  int c0 = 2*cp;
  float r0 = fmaxf(a0 + bias[c0],   0.f);
  float r1 = fmaxf(a1 + bias[c0+1], 0.f);
  out[(size_t)n*72 + cp] = (unsigned)f2bf(r0) | ((unsigned)f2bf(r1) << 16);
}

// ---------------- batchnorm stats: two-stage, atomic-free ----------------
#define BNS_GRID 512
__global__ __launch_bounds__(256) void k_bnstats1(const uint2* __restrict__ h4,
                                                  float* __restrict__ partials){
  __shared__ float red[252*8];
  int t = threadIdx.x;
  int r = t / 36, c = t - r*36;
  bool active = (t < 252);
  int rows = (N_NODESC + BNS_GRID - 1)/BNS_GRID;
  int n0 = blockIdx.x*rows, n1 = min(N_NODESC, n0+rows);
  float s[4] = {0,0,0,0}, q[4] = {0,0,0,0};
  if (active){
    for (int n = n0 + r; n < n1; n += 7){
      uint2 v = h4[(size_t)n*36 + c];
      float f0 = __uint_as_float(v.x << 16);
      float f1 = __uint_as_float(v.x & 0xFFFF0000u);
      float f2 = __uint_as_float(v.y << 16);
      float f3 = __uint_as_float(v.y & 0xFFFF0000u);
      s[0]+=f0; q[0]+=f0*f0; s[1]+=f1; q[1]+=f1*f1;
      s[2]+=f2; q[2]+=f2*f2; s[3]+=f3; q[3]+=f3*f3;
    }
    #pragma unroll
    for (int j=0;j<4;++j){
      red[(c*7+r)*8 + j]     = s[j];
      red[(c*7+r)*8 + 4 + j] = q[j];
    }
  }
  __syncthreads();
  if (t < 36){
    float ss[4]={0,0,0,0}, qq[4]={0,0,0,0};
    for (int rr=0; rr<7; ++rr){
      #pragma unroll
      for (int j=0;j<4;++j){
        ss[j] += red[(t*7+rr)*8 + j];
        qq[j] += red[(t*7+rr)*8 + 4 + j];
      }
    }
    float* p = partials + (size_t)blockIdx.x*288;
    #pragma unroll
    for (int j=0;j<4;++j){
      p[4*t+j]       = ss[j];
      p[144+4*t+j]   = qq[j];
    }
  }
}

__global__ __launch_bounds__(64) void k_bnstats2(const float* __restrict__ partials,
                                                 float* __restrict__ sums){
  int i = blockIdx.x, t = threadIdx.x;
  float s = 0.f;
  for (int b = t; b < BNS_GRID; b += 64) s += partials[(size_t)b*288 + i];
  #pragma unroll
  for (int o=32; o>0; o>>=1) s += __shfl_xor(s, o, 64);
  if (t == 0) sums[i] = s;
}

// ---------------- per-graph mean pool over bf16 hA (32 parts/graph) ----------------
__device__ int lbound(const int* a, int n, int v){
  int lo = 0, hi = n;
  while (lo < hi){ int m = (lo+hi) >> 1; if (a[m] < v) lo = m+1; else hi = m; }
  return lo;
}

__global__ __launch_bounds__(128) void k_pool(const unsigned* __restrict__ h2,
    const int* __restrict__ batch, float* __restrict__ sums, int* __restrict__ cnts){
  int g = blockIdx.x & 63, part = blockIdx.x >> 6;
  __shared__ int sb[2];
  if (threadIdx.x == 0){ sb[0] = lbound(batch, N_NODESC, g); sb[1] = lbound(batch, N_NODESC, g+1); }
  __syncthreads();
  int lo = sb[0], hi = sb[1];
  int t = threadIdx.x;
  if (t < 72){
    float a0 = 0.f, a1 = 0.f;
    for (int n = lo + part; n < hi; n += 32){
      unsigned v = h2[(size_t)n*72 + t];
      a0 += __uint_as_float(v << 16);
      a1 += __uint_as_float(v & 0xFFFF0000u);
    }
    atomicAdd(&sums[g*DIM + 2*t],   a0);
    atomicAdd(&sums[g*DIM + 2*t+1], a1);
  }
  if (t == 0 && part == 0) cnts[g] = hi - lo;
}

// ---------------- MLP head: column-parallel, BN via wave reduction ----------------
__global__ __launch_bounds__(64) void k_mlp1(const float* __restrict__ psum,
    const int* __restrict__ cnts,
    const float* __restrict__ bn3, const float* __restrict__ gam3,
    const float* __restrict__ bet3,
    const float* __restrict__ M1, const float* __restrict__ bm1,
    const float* __restrict__ gm1, const float* __restrict__ bb1,
    float* __restrict__ h1){
  __shared__ float sSc[144], sSh[144];
  int t = threadIdx.x, c = blockIdx.x;
  for (int i=t; i<144; i+=64){
    float mu  = bn3[i] * (1.f/N_NODESC);
    float var = bn3[144+i] * (1.f/N_NODESC) - mu*mu;
    float sc  = rsqrtf(var + EPSV) * gam3[i];
    sSc[i] = sc; sSh[i] = bet3[i] - mu*sc;
  }
  __syncthreads();
  float invc = 1.f / (float)max(cnts[t], 1);
  float acc = bm1[c];
  const float* pr = psum + t*144;
  for (int k=0; k<144; ++k){
    float g = fmaf(pr[k]*invc, sSc[k], sSh[k]);
    acc = fmaf(g, M1[k*72 + c], acc);
  }
  float s = acc, q = acc*acc;
  #pragma unroll
  for (int o=32; o>0; o>>=1){ s += __shfl_xor(s, o, 64); q += __shfl_xor(q, o, 64); }
  float mu = s*(1.f/64.f), var = q*(1.f/64.f) - mu*mu;
  float v = (acc - mu)*rsqrtf(var + EPSV)*gm1[c] + bb1[c];
  h1[t*72 + c] = fmaxf(v, 0.f);
}

__global__ __launch_bounds__(64) void k_mlp2(const float* __restrict__ h1,
    const float* __restrict__ M2, const float* __restrict__ bm2,
    const float* __restrict__ gm2, const float* __restrict__ bb2,
    float* __restrict__ h2){
  int t = threadIdx.x, c = blockIdx.x;
  float acc = bm2[c];
  const float* pr = h1 + t*72;
  for (int k=0; k<72; ++k) acc = fmaf(pr[k], M2[k*36 + c], acc);
  float s = acc, q = acc*acc;
  #pragma unroll
  for (int o=32; o>0; o>>=1){ s += __shfl_xor(s, o, 64); q += __shfl_xor(q, o, 64); }
  float mu = s*(1.f/64.f), var = q*(1.f/64.f) - mu*mu;
  float v = (acc - mu)*rsqrtf(var + EPSV)*gm2[c] + bb2[c];
  h2[t*36 + c] = fmaxf(v, 0.f);
}

__global__ __launch_bounds__(64) void k_mlp3(const float* __restrict__ h2,
    const float* __restrict__ M3, const float* __restrict__ bm3,
    float* __restrict__ out){
  int t = threadIdx.x, c = blockIdx.x;
  float acc = bm3[c];
  const float* pr = h2 + t*36;
  for (int k=0; k<36; ++k) acc = fmaf(pr[k], M3[k*112 + c], acc);
  out[t*112 + c] = acc;
}

extern "C" void kernel_launch(void* const* d_in, const int* in_sizes, int n_in,
                              void* d_out, int out_size, void* d_ws, size_t ws_size,
                              hipStream_t stream){
  const float* x    = (const float*)d_in[0];
  const int*   ei   = (const int*)d_in[1];
  const int*   batch= (const int*)d_in[2];
  const float* We   = (const float*)d_in[3];
  const float* be   = (const float*)d_in[4];
  const float* Wg   = (const float*)d_in[5];
  const float* a_sg = (const float*)d_in[6];
  const float* a_dg = (const float*)d_in[7];
  const float* bg   = (const float*)d_in[8];
  const float* gam  = (const float*)d_in[9];
  const float* bet  = (const float*)d_in[10];
  const float* W3   = (const float*)d_in[11];
  const float* a_s3 = (const float*)d_in[12];
  const float* a_d3 = (const float*)d_in[13];
  const float* b3   = (const float*)d_in[14];
  const float* gam3 = (const float*)d_in[15];
  const float* bet3 = (const float*)d_in[16];
  const float* M1   = (const float*)d_in[17];
  const float* bm1  = (const float*)d_in[18];
  const float* gm1  = (const float*)d_in[19];
  const float* bb1  = (const float*)d_in[20];
  const float* M2   = (const float*)d_in[21];
  const float* bm2  = (const float*)d_in[22];
  const float* gm2  = (const float*)d_in[23];
  const float* bb2  = (const float*)d_in[24];
  const float* M3   = (const float*)d_in[25];
  const float* bm3  = (const float*)d_in[26];
  float* out = (float*)d_out;

  char* ws = (char*)d_ws;
  size_t off = 0;
  auto alloc = [&](size_t bytes)->char*{
    char* p = ws + off; off += (bytes + 255) & ~(size_t)255; return p;
  };
  unsigned short* hAb = (unsigned short*)alloc((size_t)N_NODESC*DIM*2);
  unsigned short* hp  = (unsigned short*)alloc((size_t)N_NODESC*DIM*2);
  float* al_s   = (float*)alloc((size_t)N_NODESC*8*4);
  float* al_d   = (float*)alloc((size_t)N_NODESC*8*4);
  float* esc    = (float*)alloc((size_t)E_TOT*8*4);
  int* row_ptr  = (int*)alloc((size_t)(N_NODESC+1)*4);
  int* deg      = (int*)alloc((size_t)N_NODESC*4);
  int* cursor   = (int*)alloc((size_t)N_NODESC*4);
  int* scanned  = (int*)alloc((size_t)N_NODESC*4);
  int* bsum     = (int*)alloc((size_t)SCAN_NB*4);
  int* col      = (int*)alloc((size_t)E_TOT*4);
  float* bns4   = (float*)alloc(4*2*DIM*4);
  float* partials = (float*)alloc((size_t)BNS_GRID*288*4);
  float* psum   = (float*)alloc((size_t)NGRAPH*DIM*4);
  int* pcnt     = (int*)alloc(NGRAPH*4);
  float* h1buf  = (float*)alloc((size_t)NGRAPH*72*4);
  float* h2buf  = (float*)alloc((size_t)NGRAPH*36*4);
  unsigned short* Wt = (unsigned short*)alloc((size_t)160*168*2);
  float* bias2  = (float*)alloc(160*4);
  (void)ws_size; (void)n_in; (void)in_sizes; (void)out_size;

  const int GEMM_GRID = (N_NODESC + 63)/64;   // 782

  // CSR build
  hipMemsetAsync(deg, 0, (size_t)N_NODESC*4, stream);
  k_count<<<(E_TOT+255)/256, 256, 0, stream>>>(ei, deg);
  k_scan1<<<SCAN_NB, 256, 0, stream>>>(deg, scanned, bsum);
  k_scan2<<<1, 128, 0, stream>>>(bsum);
  k_scan3<<<(N_NODESC+255)/256, 256, 0, stream>>>(scanned, bsum, row_ptr, cursor);
  k_scatter<<<(E_TOT+255)/256, 256, 0, stream>>>(ei, cursor, col);

  // embed: hAb = bf16(x) @ We + be  (MFMA, LDS Wt, fused f32->bf16 A-load)
  k_prep_w<<<144, 192, 0, stream>>>(We, be, nullptr, nullptr,
                                    nullptr, nullptr, nullptr, Wt, bias2, 128, 136, 0);
  k_mfma_gemm<9,4,136,144,1><<<GEMM_GRID, 256, 0, stream>>>(
      x, Wt, bias2, hAb, nullptr, nullptr, 128, 0);

  for (int L=0; L<4; ++L){
    const float* W  = (L<3) ? (Wg  + (size_t)L*DIM*DIM) : W3;
    const float* as = (L<3) ? (a_sg + (size_t)L*8*18)   : a_s3;
    const float* ad = (L<3) ? (a_dg + (size_t)L*8*18)   : a_d3;
    const float* bb = (L<3) ? (bg  + L*DIM) : b3;
    int H = (L<3) ? 8 : 1;
    int C = (L<3) ? 18 : 144;
    const float* bnp = (L==0) ? nullptr : bns4 + (size_t)(L-1)*2*DIM;
    const float* gmp = (L==0) ? nullptr : gam + (size_t)(L-1)*DIM;
    const float* btp = (L==0) ? nullptr : bet + (size_t)(L-1)*DIM;
    // BN folded into weights; attn logits folded as 16 extra output columns
    k_prep_w<<<160, 192, 0, stream>>>(W, nullptr, as, ad,
                                      bnp, gmp, btp, Wt, bias2, 144, 168, H);
    k_mfma_gemm<10,5,168,160,0><<<GEMM_GRID, 256, 0, stream>>>(
        hAb, Wt, bias2, hp, al_s, al_d, 144, H);
    k_edge_softmax<<<(N_NODESC*H+255)/256, 256, 0, stream>>>(
        al_s, al_d, row_ptr, col, esc, H);
    k_aggregate2<<<(N_NODESC*72+255)/256, 256, 0, stream>>>(
        (const unsigned*)hp, esc, row_ptr, col, bb, (unsigned*)hAb, H, C/2);
    k_bnstats1<<<BNS_GRID, 256, 0, stream>>>((const uint2*)hAb, partials);
    k_bnstats2<<<288, 64, 0, stream>>>(partials, bns4 + (size_t)L*2*DIM);
  }

  hipMemsetAsync(psum, 0, (size_t)NGRAPH*DIM*4, stream);
  k_pool<<<NGRAPH*32, 128, 0, stream>>>((const unsigned*)hAb, batch, psum, pcnt);
  k_mlp1<<<72, 64, 0, stream>>>(psum, pcnt, bns4 + 3*2*DIM, gam3, bet3,
                                M1, bm1, gm1, bb1, h1buf);
  k_mlp2<<<36, 64, 0, stream>>>(h1buf, M2, bm2, gm2, bb2, h2buf);
  k_mlp3<<<112, 64, 0, stream>>>(h2buf, M3, bm3, out);
}